// Round 1
// baseline (803.663 us; speedup 1.0000x reference)
//
#include <hip/hip_runtime.h>
#include <math.h>

#define N_NODES 100000
#define N_EDGES 3200000
#define F_IN 64
#define HID 16
#define NC 4

__global__ __launch_bounds__(256) void k_init_deg(float* __restrict__ deg) {
    int n = blockIdx.x * blockDim.x + threadIdx.x;
    if (n < N_NODES) deg[n] = 1.0f;   // self-loop weight
}

__global__ __launch_bounds__(256) void k_deg_scatter(const int* __restrict__ col,
                                                     const float* __restrict__ ew,
                                                     float* __restrict__ deg) {
    int e = blockIdx.x * blockDim.x + threadIdx.x;
    if (e < N_EDGES) atomicAdd(&deg[col[e]], ew[e]);
}

__global__ __launch_bounds__(256) void k_dinv(float* __restrict__ deg) {
    int n = blockIdx.x * blockDim.x + threadIdx.x;
    if (n < N_NODES) {
        float d = deg[n];
        deg[n] = d > 0.0f ? rsqrtf(d) : 0.0f;
    }
}

__global__ __launch_bounds__(256) void k_norm(const int* __restrict__ row,
                                              const int* __restrict__ col,
                                              const float* __restrict__ ew,
                                              const float* __restrict__ dinv,
                                              float* __restrict__ norm) {
    int e = blockIdx.x * blockDim.x + threadIdx.x;
    if (e < N_EDGES) norm[e] = dinv[row[e]] * ew[e] * dinv[col[e]];
}

// Layer 1 transform: t = x @ W1 ; agg = b1 + dinv^2 * t  (self-loop folded in)
__global__ __launch_bounds__(256) void k_xform1(const float* __restrict__ x,
                                                const float* __restrict__ W,
                                                const float* __restrict__ b,
                                                const float* __restrict__ dinv,
                                                float* __restrict__ t,
                                                float* __restrict__ agg) {
    __shared__ float Ws[F_IN * HID];
    for (int i = threadIdx.x; i < F_IN * HID; i += blockDim.x) Ws[i] = W[i];
    __syncthreads();
    int n = blockIdx.x * blockDim.x + threadIdx.x;
    if (n >= N_NODES) return;
    float acc[HID];
#pragma unroll
    for (int j = 0; j < HID; j++) acc[j] = 0.0f;
    const float4* xp = (const float4*)(x + (size_t)n * F_IN);
#pragma unroll
    for (int k4 = 0; k4 < F_IN / 4; k4++) {
        float4 v = xp[k4];
        int k = k4 * 4;
#pragma unroll
        for (int j = 0; j < HID; j++) {
            acc[j] += v.x * Ws[(k + 0) * HID + j];
            acc[j] += v.y * Ws[(k + 1) * HID + j];
            acc[j] += v.z * Ws[(k + 2) * HID + j];
            acc[j] += v.w * Ws[(k + 3) * HID + j];
        }
    }
    float di = dinv[n];
    float sl = di * di;
#pragma unroll
    for (int j = 0; j < HID; j++) {
        t[(size_t)n * HID + j] = acc[j];
        agg[(size_t)n * HID + j] = b[j] + sl * acc[j];
    }
}

// Layers 2/3 transform: input is relu(hin) [N,HID]; t = relu(hin) @ W ; agg = b + dinv^2 * t
// Safe when agg == hin (thread reads then writes only its own row).
template <int DOUT>
__global__ __launch_bounds__(256) void k_xform(const float* __restrict__ hin,
                                               const float* __restrict__ W,
                                               const float* __restrict__ b,
                                               const float* __restrict__ dinv,
                                               float* __restrict__ t,
                                               float* __restrict__ agg) {
    __shared__ float Ws[HID * DOUT];
    for (int i = threadIdx.x; i < HID * DOUT; i += blockDim.x) Ws[i] = W[i];
    __syncthreads();
    int n = blockIdx.x * blockDim.x + threadIdx.x;
    if (n >= N_NODES) return;
    float h[HID];
    const float4* hp = (const float4*)(hin + (size_t)n * HID);
#pragma unroll
    for (int k4 = 0; k4 < HID / 4; k4++) {
        float4 v = hp[k4];
        h[k4 * 4 + 0] = fmaxf(v.x, 0.0f);
        h[k4 * 4 + 1] = fmaxf(v.y, 0.0f);
        h[k4 * 4 + 2] = fmaxf(v.z, 0.0f);
        h[k4 * 4 + 3] = fmaxf(v.w, 0.0f);
    }
    float acc[DOUT];
#pragma unroll
    for (int j = 0; j < DOUT; j++) acc[j] = 0.0f;
#pragma unroll
    for (int k = 0; k < HID; k++) {
#pragma unroll
        for (int j = 0; j < DOUT; j++) acc[j] += h[k] * Ws[k * DOUT + j];
    }
    float di = dinv[n];
    float sl = di * di;
#pragma unroll
    for (int j = 0; j < DOUT; j++) {
        t[(size_t)n * DOUT + j] = acc[j];
        agg[(size_t)n * DOUT + j] = b[j] + sl * acc[j];
    }
}

// Edge scatter: D threads per edge, feature j = tid & (D-1).
template <int D>
__global__ __launch_bounds__(256) void k_scatter(const int* __restrict__ row,
                                                 const int* __restrict__ col,
                                                 const float* __restrict__ norm,
                                                 const float* __restrict__ t,
                                                 float* __restrict__ agg) {
    int tid = blockIdx.x * blockDim.x + threadIdx.x;
    int e = tid / D;
    int j = tid & (D - 1);
    if (e >= N_EDGES) return;
    int r = row[e];
    int c = col[e];
    float v = norm[e] * t[(size_t)r * D + j];
    atomicAdd(&agg[(size_t)c * D + j], v);
}

__global__ __launch_bounds__(256) void k_logsoftmax(float* __restrict__ out) {
    int n = blockIdx.x * blockDim.x + threadIdx.x;
    if (n >= N_NODES) return;
    float4 v = ((float4*)out)[n];
    float m = fmaxf(fmaxf(v.x, v.y), fmaxf(v.z, v.w));
    float s = expf(v.x - m) + expf(v.y - m) + expf(v.z - m) + expf(v.w - m);
    float l = m + logf(s);
    ((float4*)out)[n] = make_float4(v.x - l, v.y - l, v.z - l, v.w - l);
}

extern "C" void kernel_launch(void* const* d_in, const int* in_sizes, int n_in,
                              void* d_out, int out_size, void* d_ws, size_t ws_size,
                              hipStream_t stream) {
    const float* x  = (const float*)d_in[0];
    const int*   ei = (const int*)d_in[1];   // [2, E] row-major: row then col
    const float* ew = (const float*)d_in[2];
    const float* W1 = (const float*)d_in[3];
    const float* b1 = (const float*)d_in[4];
    const float* W3 = (const float*)d_in[5];
    const float* b3 = (const float*)d_in[6];
    const float* W2 = (const float*)d_in[7];
    const float* b2 = (const float*)d_in[8];
    float* out = (float*)d_out;

    const int* row = ei;
    const int* col = ei + N_EDGES;

    float* deg  = (float*)d_ws;                  // N floats (becomes dinv in place)
    float* norm = deg + N_NODES;                 // E floats
    float* A    = norm + N_EDGES;                // N*HID floats (t buffers)
    float* B    = A + (size_t)N_NODES * HID;     // N*HID floats (agg buffers)

    const int T = 256;
    int gN  = (N_NODES + T - 1) / T;
    int gE  = (N_EDGES + T - 1) / T;
    int gE16 = (N_EDGES * HID + T - 1) / T;      // 51.2M threads
    int gE4  = (N_EDGES * NC + T - 1) / T;       // 12.8M threads

    // Degree + normalization
    k_init_deg<<<gN, T, 0, stream>>>(deg);
    k_deg_scatter<<<gE, T, 0, stream>>>(col, ew, deg);
    k_dinv<<<gN, T, 0, stream>>>(deg);
    k_norm<<<gE, T, 0, stream>>>(row, col, ew, deg, norm);

    // Layer 1: x[N,64] @ W1 -> t1(A); agg1(B) = b1 + dinv^2 * t1; scatter edges
    k_xform1<<<gN, T, 0, stream>>>(x, W1, b1, deg, A, B);
    k_scatter<HID><<<gE16, T, 0, stream>>>(row, col, norm, A, B);

    // Layer 2: relu(agg1=B) @ W3 -> t2(A); agg2(B, in place) ; scatter
    k_xform<HID><<<gN, T, 0, stream>>>(B, W3, b3, deg, A, B);
    k_scatter<HID><<<gE16, T, 0, stream>>>(row, col, norm, A, B);

    // Layer 3: relu(agg2=B) @ W2 -> t3(A, packed N*4); agg3 = d_out ; scatter
    k_xform<NC><<<gN, T, 0, stream>>>(B, W2, b2, deg, A, out);
    k_scatter<NC><<<gE4, T, 0, stream>>>(row, col, norm, A, out);

    // log_softmax in place over 4 classes
    k_logsoftmax<<<gN, T, 0, stream>>>(out);
}